// Round 2
// baseline (38.018 us; speedup 1.0000x reference)
//
#include <hip/hip_runtime.h>

#define VOC 10000

__device__ __forceinline__ float2 cmul(float2 a, float2 b) {
  return make_float2(a.x * b.x - a.y * b.y, a.x * b.y + a.y * b.x);
}
__device__ __forceinline__ float2 cmulj(float2 a, float2 b) { // a * conj(b)
  return make_float2(a.x * b.x + a.y * b.y, a.y * b.x - a.x * b.y);
}
__device__ __forceinline__ float2 cadd(float2 a, float2 b) {
  return make_float2(a.x + b.x, a.y + b.y);
}

// ---------------------------------------------------------------------------
// K1: per-vocab histograms of drug (blocks 0..63) and target (blocks 64..191)
// ---------------------------------------------------------------------------
__global__ __launch_bounds__(256) void hist_kernel(
    const int* __restrict__ drug, const int* __restrict__ target,
    int* __restrict__ hist_d, int* __restrict__ hist_t) {
  __shared__ int h[VOC];
  const int t = threadIdx.x;
  for (int i = t; i < VOC; i += 256) h[i] = 0;
  __syncthreads();
  const int b = blockIdx.x;
  const int* __restrict__ src;
  int base;
  int* dst;
  if (b < 64) { src = drug;   base = b << 12;        dst = hist_d; }
  else        { src = target; base = (b - 64) << 12; dst = hist_t; }
#pragma unroll
  for (int it = 0; it < 16; ++it) {
    int v = src[base + (it << 8) + t];
    atomicAdd(&h[v], 1);
  }
  __syncthreads();
  for (int i = t; i < VOC; i += 256) {
    int c = h[i];
    if (c) atomicAdd(&dst[i], c);
  }
}

// ---------------------------------------------------------------------------
// K2: gram[br][a][b] = sum_v cnt[v] * E[v][a] * E[v][b]   (row 0 forced to 0:
// padding_idx). 64 blocks per branch, 157 vocab rows each, LDS-staged.
// ---------------------------------------------------------------------------
__global__ __launch_bounds__(256) void gram_kernel(
    const float* __restrict__ Ed, const float* __restrict__ Et,
    const int* __restrict__ hd, const int* __restrict__ ht,
    float* __restrict__ gram /* [2][256] */) {
  __shared__ float se[128 * 16];
  __shared__ float sc[128];
  const int t = threadIdx.x;
  const int br = blockIdx.x >> 6;
  const int local = blockIdx.x & 63;
  const float* __restrict__ E = br ? Et : Ed;
  const int* __restrict__ H = br ? ht : hd;
  const int a = t >> 4, col = t & 15;
  float acc = 0.f;
  const int start = local * 157;
  const int end = (start + 157 < VOC) ? (start + 157) : VOC;
  for (int chunk = start; chunk < end; chunk += 128) {
    const int n = (end - chunk < 128) ? (end - chunk) : 128;
    for (int e = t; e < n * 16; e += 256)
      se[e] = E[chunk * 16 + e];
    if (t < n) {
      int v = chunk + t;
      sc[t] = (v == 0) ? 0.f : (float)H[v];
    }
    __syncthreads();
    for (int r = 0; r < n; ++r)
      acc = fmaf(sc[r] * se[(r << 4) + a], se[(r << 4) + col], acc);
    __syncthreads();
  }
  atomicAdd(&gram[(br << 8) + t], acc);
}

// ---------------------------------------------------------------------------
// K3: everything downstream of the two grams, in one 256-thread block.
//   conv1 -> c (4x16); H = c c^T (= pre); X = c^T c; rho = G H G^T / tr(H^2)
//   U = (C (x) D) P (A (x) B); CNOT ring P is bit-linear:
//     pih(j) = g(jh, par(jl)),  pil(j) = f(par(jh), jl)
//   => M = U (G1 (x) G2) = sum over s=(delta,eps) of Ahat_s (x) Bhat_s
//   diag(U rho U^H)[m] = sum_{ss'} Qa_{ss'}[mh] * Qb_{ss'}[ml]
//   d_m[i] = Re sum_{ss'} (sum_mh Qa) * (sum_ml sign_i(ml) Qb) / (sd*st)
//   then conv2 (3x3 pad1) -> fc1 -> fc2 -> f32 scalar.
// ---------------------------------------------------------------------------
__global__ __launch_bounds__(256) void tail_kernel(
    const float* __restrict__ gram, // [2][256]
    const float* __restrict__ dw1, const float* __restrict__ db1,
    const float* __restrict__ tw1, const float* __restrict__ tb1,
    const float* __restrict__ dw2, const float* __restrict__ db2,
    const float* __restrict__ tw2, const float* __restrict__ tb2,
    const float* __restrict__ mw,
    const float* __restrict__ f1w, const float* __restrict__ f1b,
    const float* __restrict__ f2w, const float* __restrict__ f2b,
    float* __restrict__ out) {

  __shared__ float sgram[512];
  __shared__ float wconv[2][256];
  __shared__ float cmat[2][4][16];   // c (4x16) per branch
  __shared__ float Hmat[2][16];      // H = c c^T (4x4) per branch (= pre)
  __shared__ float ssum[2];          // tr(H^2) = tr(X^2)
  __shared__ float2 rotm[2][8][4];   // [layer][qubit][2x2]
  __shared__ float2 M16[4][256];     // A,B (layer1 hi/lo), C,D (layer2 hi/lo)
  __shared__ int gtab[2][16];        // g(jh, eps)  -> high nibble of pi
  __shared__ int ftab[2][16];        // f(delta, jl)-> low  nibble of pi
  __shared__ float2 pab[2][2][16][4];  // [A/B][branch][row16][col4]
  __shared__ float2 Ahs[2][4][16][4];  // [order][s][mh][ca]
  __shared__ float2 Bhs[2][4][16][4];  // [order][s][ml][cb]
  __shared__ float2 Qa[2][16][16];     // [order][s*4+s'][mh]
  __shared__ float2 Qb[2][16][16];     // [order][s*4+s'][ml]
  __shared__ float2 SQa[2][16];
  __shared__ float2 SQb[2][4][16];
  __shared__ float dmv[2][4];          // d_m, t_m
  __shared__ float xv[128];
  __shared__ float hv[32];

  const int t = threadIdx.x;
  const float W_MUL = 0.6324555320336759f; // sqrt(2/5)

  // R0: stage grams + conv1 weights
  sgram[t] = gram[t];
  sgram[t + 256] = gram[t + 256];
  wconv[0][t] = dw1[t];
  wconv[1][t] = tw1[t];
  __syncthreads();

  // R1: conv1 (pad left1/right2, k=4) ; rot matrices ; permutation tables
  if (t < 128) {
    const int br = t >> 6, o = (t >> 4) & 3, p = t & 15;
    float s = br ? tb1[o] : db1[o];
    const float* g = &sgram[br << 8];
    const float* w = wconv[br];
    for (int i = 0; i < 16; ++i) {
#pragma unroll
      for (int k = 0; k < 4; ++k) {
        int q = p + k - 1;
        if (q >= 0 && q < 16) s = fmaf(w[(o << 6) + (i << 2) + k], g[(i << 4) + q], s);
      }
    }
    cmat[br][o][p] = s;
  } else if (t < 144) {
    // Rz @ Ry @ Rx per (layer, qubit)
    const int idx = t - 128, l = idx >> 3, q = idx & 7;
    float hx = 0.5f * W_MUL * mw[q * 6 + l * 3 + 0];
    float hy = 0.5f * W_MUL * mw[q * 6 + l * 3 + 1];
    float hz = 0.5f * W_MUL * mw[q * 6 + l * 3 + 2];
    float cx = cosf(hx), sx = sinf(hx);
    float cy = cosf(hy), sy = sinf(hy);
    float cz = cosf(hz), sz = sinf(hz);
    float2 m00 = make_float2(cy * cx, sy * sx);
    float2 m01 = make_float2(-sy * cx, -cy * sx);
    float2 m10 = make_float2(sy * cx, -cy * sx);
    float2 m11 = make_float2(cy * cx, -sy * sx);
    float2 e0 = make_float2(cz, -sz), e1 = make_float2(cz, sz);
    rotm[l][q][0] = cmul(e0, m00);
    rotm[l][q][1] = cmul(e0, m01);
    rotm[l][q][2] = cmul(e1, m10);
    rotm[l][q][3] = cmul(e1, m11);
  } else if (t < 208) {
    // CNOT-ring permutation bits: p0 = b1^..^b7 ; pq = b0^..^bq (q>=1)
    const int idx = t - 144;
    const int which = idx >> 5, par = (idx >> 4) & 1, nib = idx & 15;
    int b0 = (nib >> 3) & 1, b1 = (nib >> 2) & 1, b2 = (nib >> 1) & 1, b3 = nib & 1;
    if (which == 0) { // g(jh, eps): eps = par(jl); p0 independent of b0
      int p0 = b1 ^ b2 ^ b3 ^ par;
      int p1 = b0 ^ b1, p2 = p1 ^ b2, p3 = p2 ^ b3;
      gtab[par][nib] = (p0 << 3) | (p1 << 2) | (p2 << 1) | p3;
    } else {          // f(delta, jl): delta = par(jh); nib bits are qubits 4..7
      int p4 = par ^ b0, p5 = p4 ^ b1, p6 = p5 ^ b2, p7 = p6 ^ b3;
      ftab[par][nib] = (p4 << 3) | (p5 << 2) | (p6 << 1) | p7;
    }
  }
  __syncthreads();

  // R2: H = c c^T ; build A,B,C,D (kron of four 2x2 rots, qubit0 = MSB)
  if (t < 32) {
    const int br = t >> 4, a = (t >> 2) & 3, b = t & 3;
    float s = 0.f;
#pragma unroll
    for (int p = 0; p < 16; ++p) s = fmaf(cmat[br][a][p], cmat[br][b][p], s);
    Hmat[br][(a << 2) + b] = s;
  }
#pragma unroll
  for (int mat = 0; mat < 4; ++mat) {
    const int r = t >> 4, c = t & 15;
    const int l = mat >> 1, qb = (mat & 1) << 2;
    float2 prod = rotm[l][qb + 0][(((r >> 3) & 1) << 1) | ((c >> 3) & 1)];
    prod = cmul(prod, rotm[l][qb + 1][(((r >> 2) & 1) << 1) | ((c >> 2) & 1)]);
    prod = cmul(prod, rotm[l][qb + 2][(((r >> 1) & 1) << 1) | ((c >> 1) & 1)]);
    prod = cmul(prod, rotm[l][qb + 3][((r & 1) << 1) | (c & 1)]);
    M16[mat][t] = prod;
  }
  __syncthreads();

  // R3: ssum = tr(H^2) ; pab = {A,B} x {Gd,Gt}  (G = c^T, real)
  if (t < 2) {
    float s = 0.f;
#pragma unroll
    for (int i = 0; i < 16; ++i) s = fmaf(Hmat[t][i], Hmat[t][i], s);
    ssum[t] = s;
  }
  {
    const int op = t >> 7, br = (t >> 6) & 1, r = (t >> 2) & 15, ca = t & 3;
    float2 s = make_float2(0.f, 0.f);
#pragma unroll
    for (int k = 0; k < 16; ++k) {
      float gk = cmat[br][ca][k]; // G[k][ca] = c[ca][k]
      float2 m = M16[op][(r << 4) + k];
      s.x = fmaf(m.x, gk, s.x);
      s.y = fmaf(m.y, gk, s.y);
    }
    pab[op][br][r][ca] = s;
  }
  __syncthreads();

  // R4: parity-split: Ahat_{(d,e)}[mh,ca] = sum_{jh:par=d} C[mh,g(jh,e)] (A Gd)[jh,ca]
  //                   Bhat_{(d,e)}[ml,cb] = sum_{jl:par=e} D[ml,f(d,jl)] (B Gt)[jl,cb]
#pragma unroll
  for (int e0 = 0; e0 < 4; ++e0) {
    const int e = t + (e0 << 8);
    const int isB = e >> 9, rest = e & 511;
    const int ord = rest >> 8, s = (rest >> 6) & 3, row = (rest >> 2) & 15, cc = rest & 3;
    const int delta = s >> 1, eps = s & 1;
    float2 acc = make_float2(0.f, 0.f);
    if (!isB) {
      const int br1 = ord; // order0 = (d,t): first subsystem d
      for (int jh = 0; jh < 16; ++jh) {
        if ((__popc(jh) & 1) != delta) continue;
        acc = cadd(acc, cmul(M16[2][(row << 4) + gtab[eps][jh]], pab[0][br1][jh][cc]));
      }
      Ahs[ord][s][row][cc] = acc;
    } else {
      const int br2 = ord ^ 1;
      for (int jl = 0; jl < 16; ++jl) {
        if ((__popc(jl) & 1) != eps) continue;
        acc = cadd(acc, cmul(M16[3][(row << 4) + ftab[delta][jl]], pab[1][br2][jl][cc]));
      }
      Bhs[ord][s][row][cc] = acc;
    }
  }
  __syncthreads();

  // R5: Qa_{ss'}[mh] = sum_{a,b} H1[a,b] As[mh,a] conj(As'[mh,b]) ; Qb analog, H2
#pragma unroll
  for (int e0 = 0; e0 < 4; ++e0) {
    const int e = t + (e0 << 8);
    const int isb = e >> 9, rest = e & 511;
    const int ord = rest >> 8, ss = (rest >> 4) & 15, row = rest & 15;
    const int s = ss >> 2, sp = ss & 3;
    float2 u[4], w[4];
    const float* Hx;
    if (!isb) {
      Hx = Hmat[ord];
#pragma unroll
      for (int k = 0; k < 4; ++k) { u[k] = Ahs[ord][s][row][k]; w[k] = Ahs[ord][sp][row][k]; }
    } else {
      Hx = Hmat[ord ^ 1];
#pragma unroll
      for (int k = 0; k < 4; ++k) { u[k] = Bhs[ord][s][row][k]; w[k] = Bhs[ord][sp][row][k]; }
    }
    float2 acc = make_float2(0.f, 0.f);
#pragma unroll
    for (int a = 0; a < 4; ++a)
#pragma unroll
      for (int b = 0; b < 4; ++b) {
        float2 v = cmulj(u[a], w[b]);
        float hh = Hx[(a << 2) + b];
        acc.x = fmaf(hh, v.x, acc.x);
        acc.y = fmaf(hh, v.y, acc.y);
      }
    if (!isb) Qa[ord][ss][row] = acc;
    else      Qb[ord][ss][row] = acc;
  }
  __syncthreads();

  // R6: SQa = sum_mh Qa ; SQb[i] = sum_ml sign_i(ml) Qb
  if (t < 32) {
    const int ord = t >> 4, ss = t & 15;
    float2 acc = make_float2(0.f, 0.f);
#pragma unroll
    for (int r = 0; r < 16; ++r) acc = cadd(acc, Qa[ord][ss][r]);
    SQa[ord][ss] = acc;
  } else if (t >= 128) {
    const int idx = t - 128;
    const int ord = idx >> 6, i = (idx >> 4) & 3, ss = idx & 15;
    float2 acc = make_float2(0.f, 0.f);
#pragma unroll
    for (int ml = 0; ml < 16; ++ml) {
      float sg = ((ml >> (3 - i)) & 1) ? -1.f : 1.f;
      float2 q = Qb[ord][ss][ml];
      acc.x = fmaf(sg, q.x, acc.x);
      acc.y = fmaf(sg, q.y, acc.y);
    }
    SQb[ord][i][ss] = acc;
  }
  __syncthreads();

  // R7: d_m / t_m = Re(sum_ss' SQa*SQb) / (sd*st)
  if (t < 8) {
    const int ord = t >> 2, i = t & 3;
    float acc = 0.f;
#pragma unroll
    for (int ss = 0; ss < 16; ++ss) {
      float2 a = SQa[ord][ss], b = SQb[ord][i][ss];
      acc += a.x * b.x - a.y * b.y;
    }
    dmv[ord][i] = acc / (ssum[0] * ssum[1]);
  }
  __syncthreads();

  // R8: conv2 3x3 pad1 on [pre(=H), m m^T] -> xv[128] in concat(d2,t2) order
  if (t < 128) {
    const int br = t >> 6, idx = t & 63;
    const int o = idx >> 4, yy = (idx >> 2) & 3, xx = idx & 3;
    const float* w2 = br ? tw2 : dw2;
    float s = br ? tb2[o] : db2[o];
    for (int ch = 0; ch < 2; ++ch)
      for (int ky = 0; ky < 3; ++ky)
        for (int kx = 0; kx < 3; ++kx) {
          int iy = yy + ky - 1, ix = xx + kx - 1;
          if (iy < 0 || iy > 3 || ix < 0 || ix > 3) continue;
          float inv = (ch == 0) ? Hmat[br][(iy << 2) + ix] : dmv[br][iy] * dmv[br][ix];
          s = fmaf(w2[o * 18 + ch * 9 + ky * 3 + kx], inv, s);
        }
    xv[(br << 6) + idx] = s;
  }
  __syncthreads();

  // R9: fc1 + leaky_relu(0.01)
  if (t < 32) {
    float s = f1b[t];
    for (int k = 0; k < 128; ++k) s = fmaf(xv[k], f1w[(t << 7) + k], s);
    hv[t] = s > 0.f ? s : 0.01f * s;
  }
  __syncthreads();

  // R10: fc2 + leaky_relu -> f32 out
  if (t == 0) {
    float s = f2b[0];
#pragma unroll
    for (int k = 0; k < 32; ++k) s = fmaf(hv[k], f2w[k], s);
    s = s > 0.f ? s : 0.01f * s;
    out[0] = s;
  }
}

extern "C" void kernel_launch(void* const* d_in, const int* in_sizes, int n_in,
                              void* d_out, int out_size, void* d_ws, size_t ws_size,
                              hipStream_t stream) {
  const int* drug = (const int*)d_in[0];
  const int* target = (const int*)d_in[1];
  const float* embd = (const float*)d_in[2];
  const float* embt = (const float*)d_in[3];
  const float* dw1 = (const float*)d_in[4];
  const float* db1 = (const float*)d_in[5];
  const float* tw1 = (const float*)d_in[6];
  const float* tb1 = (const float*)d_in[7];
  const float* dw2 = (const float*)d_in[8];
  const float* db2 = (const float*)d_in[9];
  const float* tw2 = (const float*)d_in[10];
  const float* tb2 = (const float*)d_in[11];
  const float* mw = (const float*)d_in[12];
  const float* f1w = (const float*)d_in[13];
  const float* f1b = (const float*)d_in[14];
  const float* f2w = (const float*)d_in[15];
  const float* f2b = (const float*)d_in[16];

  int* hist_d = (int*)d_ws;
  int* hist_t = hist_d + VOC;
  float* gram = (float*)((char*)d_ws + 2 * VOC * 4); // [2][256]

  // zero hist (2*10000 int) + gram (512 float)
  hipMemsetAsync(d_ws, 0, 2 * VOC * 4 + 512 * 4, stream);
  hist_kernel<<<dim3(192), dim3(256), 0, stream>>>(drug, target, hist_d, hist_t);
  gram_kernel<<<dim3(128), dim3(256), 0, stream>>>(embd, embt, hist_d, hist_t, gram);
  tail_kernel<<<dim3(1), dim3(256), 0, stream>>>(gram, dw1, db1, tw1, tb1,
                                                 dw2, db2, tw2, tb2, mw,
                                                 f1w, f1b, f2w, f2b,
                                                 (float*)d_out);
}